// Round 7
// baseline (466.838 us; speedup 1.0000x reference)
//
#include <hip/hip_runtime.h>
#include <hip/hip_bf16.h>
#include <cstdint>

typedef __attribute__((ext_vector_type(4))) float f32x4;
typedef __attribute__((ext_vector_type(8))) short bf16x8;
typedef __attribute__((ext_vector_type(2))) unsigned int u32x2;
typedef __attribute__((ext_vector_type(4))) unsigned int u32x4;

__device__ __forceinline__ unsigned short f2bf(float f){
  union { float f; unsigned int u; } v; v.f = f;
  unsigned int u = v.u;
  u += 0x7FFFu + ((u >> 16) & 1u);   // round-to-nearest-even
  return (unsigned short)(u >> 16);
}

// ---------------------------------------------------------------- cvt f32->bf16
__global__ __launch_bounds__(256) void cvt_bf16(const float* __restrict__ in,
                                                unsigned short* __restrict__ out,
                                                int n4){
  int i = blockIdx.x * 256 + threadIdx.x;
  if (i < n4){
    float4 v = ((const float4*)in)[i];
    ushort4 o;
    o.x = f2bf(v.x); o.y = f2bf(v.y); o.z = f2bf(v.z); o.w = f2bf(v.w);
    ((ushort4*)out)[i] = o;
  }
}

// ---------------------------------------------------------------- fused QKV GEMM
__global__ __launch_bounds__(256) void qkv_gemm(
    const unsigned short* __restrict__ A,
    const unsigned short* __restrict__ W0,
    const unsigned short* __restrict__ W1,
    const unsigned short* __restrict__ W2,
    const float* __restrict__ b0,
    const float* __restrict__ b1,
    const float* __restrict__ b2,
    unsigned short* __restrict__ Qo,
    unsigned short* __restrict__ Ko,
    unsigned short* __restrict__ Vto)
{
  __shared__ unsigned short As[2][128*64];
  __shared__ unsigned short Bs[2][128*64];

  const int K = 1024;
  const int tid = threadIdx.x;
  const int l   = tid & 63;
  const int wid = tid >> 6;
  const int g   = l >> 4;
  const int li  = l & 15;
  const int widx = blockIdx.x >> 3;
  const int m0  = blockIdx.y * 128;
  const int n0  = (blockIdx.x & 7) * 128;
  const int wm  = (wid >> 1) * 64;
  const int wn  = (wid & 1) * 64;
  const int srow = tid >> 3;
  const int sck  = tid & 7;

  const unsigned short* Bw = (widx == 0) ? W0 : ((widx == 1) ? W1 : W2);
  const float* bias        = (widx == 0) ? b0 : ((widx == 1) ? b1 : b2);

  const unsigned short* Ag = A  + (size_t)(m0 + srow) * K + sck * 8;
  const unsigned short* Bg = Bw + (size_t)(n0 + srow) * K + sck * 8;

  f32x4 acc[4][4] = {};
  bf16x8 ra[4], rb[4];
  const int NT = K >> 6;

  #pragma unroll
  for (int r = 0; r < 4; ++r){
    ra[r] = *(const bf16x8*)(Ag + (size_t)(r*32) * K);
    rb[r] = *(const bf16x8*)(Bg + (size_t)(r*32) * K);
  }
  #pragma unroll
  for (int r = 0; r < 4; ++r){
    const int row = srow + r*32;
    const int ck  = sck ^ (row & 7);
    *(bf16x8*)(&As[0][row*64 + ck*8]) = ra[r];
    *(bf16x8*)(&Bs[0][row*64 + ck*8]) = rb[r];
  }
  __syncthreads();

  int cur = 0;
  for (int kt = 0; kt < NT; ++kt){
    if (kt + 1 < NT){
      const int kof = (kt + 1) << 6;
      #pragma unroll
      for (int r = 0; r < 4; ++r){
        ra[r] = *(const bf16x8*)(Ag + (size_t)(r*32) * K + kof);
        rb[r] = *(const bf16x8*)(Bg + (size_t)(r*32) * K + kof);
      }
    }
    #pragma unroll
    for (int kk = 0; kk < 2; ++kk){
      bf16x8 af[4], bfr[4];
      #pragma unroll
      for (int f = 0; f < 4; ++f){
        const int rowa = wm + f*16 + li;
        const int cka  = (kk*4 + g) ^ (rowa & 7);
        af[f] = *(const bf16x8*)(&As[cur][rowa*64 + cka*8]);
        const int rowb = wn + f*16 + li;
        const int ckb  = (kk*4 + g) ^ (rowb & 7);
        bfr[f] = *(const bf16x8*)(&Bs[cur][rowb*64 + ckb*8]);
      }
      #pragma unroll
      for (int fm = 0; fm < 4; ++fm)
        #pragma unroll
        for (int fn = 0; fn < 4; ++fn)
          acc[fm][fn] = __builtin_amdgcn_mfma_f32_16x16x32_bf16(af[fm], bfr[fn], acc[fm][fn], 0, 0, 0);
    }
    __syncthreads();
    if (kt + 1 < NT){
      #pragma unroll
      for (int r = 0; r < 4; ++r){
        const int row = srow + r*32;
        const int ck  = sck ^ (row & 7);
        *(bf16x8*)(&As[cur^1][row*64 + ck*8]) = ra[r];
        *(bf16x8*)(&Bs[cur^1][row*64 + ck*8]) = rb[r];
      }
      __syncthreads();
    }
    cur ^= 1;
  }

  unsigned short* Oqk = (widx == 0) ? Qo : Ko;
  #pragma unroll
  for (int fn = 0; fn < 4; ++fn){
    const int col = n0 + wn + fn*16 + li;
    const float bv = bias[col];
    #pragma unroll
    for (int fm = 0; fm < 4; ++fm){
      #pragma unroll
      for (int j = 0; j < 4; ++j){
        const int row = m0 + wm + fm*16 + g*4 + j;
        const float v = acc[fm][fn][j] + bv;
        if (widx < 2){
          Oqk[(size_t)row * 1024 + col] = f2bf(v);
        } else {
          const int bb = row >> 11;
          const int s  = row & 2047;
          Vto[((size_t)(bb*1024 + col)) * 2048 + s] = f2bf(v);
        }
      }
    }
  }
}

// ---------------------------------------------------------------- out-proj GEMM (f32 out)
__global__ __launch_bounds__(256) void gemm_bt(
    const unsigned short* __restrict__ A,
    const unsigned short* __restrict__ Bw,
    const float* __restrict__ bias,
    float* __restrict__ outp,
    int M, int N, int K)
{
  __shared__ unsigned short As[2][128*64];
  __shared__ unsigned short Bs[2][128*64];

  const int tid = threadIdx.x;
  const int l   = tid & 63;
  const int wid = tid >> 6;
  const int g   = l >> 4;
  const int li  = l & 15;
  const int m0  = blockIdx.y * 128;
  const int n0  = blockIdx.x * 128;
  const int wm  = (wid >> 1) * 64;
  const int wn  = (wid & 1) * 64;
  const int srow = tid >> 3;
  const int sck  = tid & 7;

  const unsigned short* Ag = A  + (size_t)(m0 + srow) * K + sck * 8;
  const unsigned short* Bg = Bw + (size_t)(n0 + srow) * K + sck * 8;

  f32x4 acc[4][4] = {};
  bf16x8 ra[4], rb[4];
  const int NT = K >> 6;

  #pragma unroll
  for (int r = 0; r < 4; ++r){
    ra[r] = *(const bf16x8*)(Ag + (size_t)(r*32) * K);
    rb[r] = *(const bf16x8*)(Bg + (size_t)(r*32) * K);
  }
  #pragma unroll
  for (int r = 0; r < 4; ++r){
    const int row = srow + r*32;
    const int ck  = sck ^ (row & 7);
    *(bf16x8*)(&As[0][row*64 + ck*8]) = ra[r];
    *(bf16x8*)(&Bs[0][row*64 + ck*8]) = rb[r];
  }
  __syncthreads();

  int cur = 0;
  for (int kt = 0; kt < NT; ++kt){
    if (kt + 1 < NT){
      const int kof = (kt + 1) << 6;
      #pragma unroll
      for (int r = 0; r < 4; ++r){
        ra[r] = *(const bf16x8*)(Ag + (size_t)(r*32) * K + kof);
        rb[r] = *(const bf16x8*)(Bg + (size_t)(r*32) * K + kof);
      }
    }
    #pragma unroll
    for (int kk = 0; kk < 2; ++kk){
      bf16x8 af[4], bfr[4];
      #pragma unroll
      for (int f = 0; f < 4; ++f){
        const int rowa = wm + f*16 + li;
        const int cka  = (kk*4 + g) ^ (rowa & 7);
        af[f] = *(const bf16x8*)(&As[cur][rowa*64 + cka*8]);
        const int rowb = wn + f*16 + li;
        const int ckb  = (kk*4 + g) ^ (rowb & 7);
        bfr[f] = *(const bf16x8*)(&Bs[cur][rowb*64 + ckb*8]);
      }
      #pragma unroll
      for (int fm = 0; fm < 4; ++fm)
        #pragma unroll
        for (int fn = 0; fn < 4; ++fn)
          acc[fm][fn] = __builtin_amdgcn_mfma_f32_16x16x32_bf16(af[fm], bfr[fn], acc[fm][fn], 0, 0, 0);
    }
    __syncthreads();
    if (kt + 1 < NT){
      #pragma unroll
      for (int r = 0; r < 4; ++r){
        const int row = srow + r*32;
        const int ck  = sck ^ (row & 7);
        *(bf16x8*)(&As[cur^1][row*64 + ck*8]) = ra[r];
        *(bf16x8*)(&Bs[cur^1][row*64 + ck*8]) = rb[r];
      }
      __syncthreads();
    }
    cur ^= 1;
  }

  #pragma unroll
  for (int fn = 0; fn < 4; ++fn){
    const int col = n0 + wn + fn*16 + li;
    const float bv = bias[col];
    #pragma unroll
    for (int fm = 0; fm < 4; ++fm){
      #pragma unroll
      for (int j = 0; j < 4; ++j){
        const int row = m0 + wm + fm*16 + g*4 + j;
        outp[(size_t)row * N + col] = acc[fm][fn][j] + bv;
      }
    }
  }
}

// ---------------------------------------------------------------- fused attention (R6)
// block = (b, h, 16 q-rows), 512 threads (8 waves). wave w owns key range [w*256, w*256+256).
// Two-pass: phase 1 computes denominators (QK^T + exp + sum, P discarded, 1 barrier).
// Phase 2 recomputes QK^T per 32-key chunk, normalizes in-reg, stores attn with PLAIN
// (through-L2) f32x4 stores spread across the loop, packs P->bf16 via a tiny 1.25KB/wave
// LDS staging (wave-local, lgkmcnt-fenced) into the MFMA A-fragment, and accumulates PV.
// No 64KB P buffer, no nontemporal stores, 2 barriers total, LDS ~33KB.
__global__ __launch_bounds__(512, 4) void attn_fused(
    const unsigned short* __restrict__ Qb,   // [4096][1024] bf16
    const unsigned short* __restrict__ Kb,   // [4096][1024] bf16
    const unsigned short* __restrict__ Vt,   // [2048][2048] bf16  ([b*1024+hid][s])
    float* __restrict__ attn,                // [2][16][2048][2048] f32
    unsigned short* __restrict__ ctxb)       // [4096][1024] bf16
{
  __shared__ float red[128];
  __shared__ __align__(16) unsigned int stag[8192];  // 32KB: per-wave P staging, then ctxred
  float* ctxred = (float*)stag;                      // [8][16][64] f32 (after phase 2)

  const int tid = threadIdx.x;
  const int l   = tid & 63;
  const int w   = tid >> 6;
  const int g   = l >> 4;     // 0..3
  const int li  = l & 15;     // q-row within block
  const int q0  = blockIdx.x * 16;
  const int bh  = blockIdx.y;
  const int b   = bh >> 4;
  const int h   = bh & 15;

  // Q fragments (B-operand: col = li = q-row, k = g*8+j within each 32-wide k-step)
  const size_t qrow = (size_t)(b*2048 + q0 + li) * 1024 + h*64 + g*8;
  const bf16x8 aq0 = *(const bf16x8*)(Qb + qrow);
  const bf16x8 aq1 = *(const bf16x8*)(Qb + qrow + 32);

  const unsigned short* Kbase = Kb + (size_t)(b*2048) * 1024 + h*64 + g*8;

  // ---- phase 1: denominators only. s[cf][j] = S[key=w*256+cf*16+g*4+j][q=li]
  float ls = 0.f;
  #pragma unroll 4
  for (int cf = 0; cf < 16; ++cf){
    const unsigned short* kr = Kbase + (size_t)(w*256 + cf*16 + li) * 1024;
    const bf16x8 bk0 = *(const bf16x8*)(kr);
    const bf16x8 bk1 = *(const bf16x8*)(kr + 32);
    f32x4 t = {};
    t = __builtin_amdgcn_mfma_f32_16x16x32_bf16(bk0, aq0, t, 0, 0, 0);
    t = __builtin_amdgcn_mfma_f32_16x16x32_bf16(bk1, aq1, t, 0, 0, 0);
    ls += __expf(t[0] * 0.125f) + __expf(t[1] * 0.125f)
        + __expf(t[2] * 0.125f) + __expf(t[3] * 0.125f);
  }
  ls += __shfl_xor(ls, 16);
  ls += __shfl_xor(ls, 32);
  if (l < 16) red[w*16 + l] = ls;
  __syncthreads();

  float dsum = 0.f;
  #pragma unroll
  for (int ww = 0; ww < 8; ++ww) dsum += red[ww*16 + li];
  const float rv = 1.0f / dsum;     // 1/denom for q-row = li (per-lane)

  // ---- phase 2: 8 chunks of 32 keys; recompute, normalize, store attn, PV.
  unsigned int* ms = stag + w*320;  // my wave's staging: 16 rows x 20 u32 (80B stride)
  f32x4 pv[4] = {};
  const unsigned short* Vbase = Vt + (size_t)(b*1024 + h*64) * 2048 + w*256;
  float* arow = attn + ((size_t)bh * 2048 + q0 + li) * 2048 + w*256;

  #pragma unroll
  for (int ch = 0; ch < 8; ++ch){
    // QK^T for the chunk's two 16-key tiles
    const unsigned short* kr0 = Kbase + (size_t)(w*256 + ch*32 +      li) * 1024;
    const unsigned short* kr1 = Kbase + (size_t)(w*256 + ch*32 + 16 + li) * 1024;
    const bf16x8 a00 = *(const bf16x8*)(kr0);
    const bf16x8 a01 = *(const bf16x8*)(kr0 + 32);
    const bf16x8 a10 = *(const bf16x8*)(kr1);
    const bf16x8 a11 = *(const bf16x8*)(kr1 + 32);
    f32x4 s0 = {}, s1 = {};
    s0 = __builtin_amdgcn_mfma_f32_16x16x32_bf16(a00, aq0, s0, 0, 0, 0);
    s0 = __builtin_amdgcn_mfma_f32_16x16x32_bf16(a01, aq1, s0, 0, 0, 0);
    s1 = __builtin_amdgcn_mfma_f32_16x16x32_bf16(a10, aq0, s1, 0, 0, 0);
    s1 = __builtin_amdgcn_mfma_f32_16x16x32_bf16(a11, aq1, s1, 0, 0, 0);

    f32x4 p0, p1;
    #pragma unroll
    for (int j = 0; j < 4; ++j){
      p0[j] = __expf(s0[j] * 0.125f) * rv;
      p1[j] = __expf(s1[j] * 0.125f) * rv;
    }

    // attn stores: plain (through-L2) f32x4; per chunk each row gets a full 128B line
    *(f32x4*)(arow + ch*32 +      g*4) = p0;
    *(f32x4*)(arow + ch*32 + 16 + g*4) = p1;

    // pack P -> bf16 pairs, stage in wave-local LDS (u32 index = key-pair within chunk)
    const unsigned int u0 = (unsigned int)f2bf(p0[0]) | ((unsigned int)f2bf(p0[1]) << 16);
    const unsigned int u1 = (unsigned int)f2bf(p0[2]) | ((unsigned int)f2bf(p0[3]) << 16);
    const unsigned int u2 = (unsigned int)f2bf(p1[0]) | ((unsigned int)f2bf(p1[1]) << 16);
    const unsigned int u3 = (unsigned int)f2bf(p1[2]) | ((unsigned int)f2bf(p1[3]) << 16);
    u32x2 w0; w0[0] = u0; w0[1] = u1;
    u32x2 w1; w1[0] = u2; w1[1] = u3;
    *(u32x2*)(ms + li*20 +     g*2) = w0;   // keys (g*4..g*4+3)        -> pairs g*2, g*2+1
    *(u32x2*)(ms + li*20 + 8 + g*2) = w1;   // keys (16+g*4..16+g*4+3)  -> pairs 8+g*2, +1

    // V loads issued before the LDS fence so HBM/L2 latency hides under it
    const bf16x8 vb0 = *(const bf16x8*)(Vbase + (size_t)(     li) * 2048 + ch*32 + g*8);
    const bf16x8 vb1 = *(const bf16x8*)(Vbase + (size_t)(16 + li) * 2048 + ch*32 + g*8);
    const bf16x8 vb2 = *(const bf16x8*)(Vbase + (size_t)(32 + li) * 2048 + ch*32 + g*8);
    const bf16x8 vb3 = *(const bf16x8*)(Vbase + (size_t)(48 + li) * 2048 + ch*32 + g*8);

    asm volatile("s_waitcnt lgkmcnt(0)" ::: "memory");
    __builtin_amdgcn_sched_barrier(0);

    // A-fragment: P[q=li][k=g*8..g*8+7] = u32 pairs g*4..g*4+3 of row li
    const u32x4 pk = *(const u32x4*)(ms + li*20 + g*4);
    const bf16x8 pa = __builtin_bit_cast(bf16x8, pk);

    pv[0] = __builtin_amdgcn_mfma_f32_16x16x32_bf16(pa, vb0, pv[0], 0, 0, 0);
    pv[1] = __builtin_amdgcn_mfma_f32_16x16x32_bf16(pa, vb1, pv[1], 0, 0, 0);
    pv[2] = __builtin_amdgcn_mfma_f32_16x16x32_bf16(pa, vb2, pv[2], 0, 0, 0);
    pv[3] = __builtin_amdgcn_mfma_f32_16x16x32_bf16(pa, vb3, pv[3], 0, 0, 0);
  }

  __syncthreads();                            // staging dead; reuse stag as ctxred
  #pragma unroll
  for (int df = 0; df < 4; ++df){
    #pragma unroll
    for (int j = 0; j < 4; ++j)
      ctxred[w*1024 + (g*4 + j)*64 + df*16 + li] = pv[df][j];
  }
  __syncthreads();
  {
    const int idx = tid * 2;                  // 512 threads x 2 = 16*64 outputs
    const int r = idx >> 6;
    const int d = idx & 63;
    float v0 = 0.f, v1 = 0.f;
    #pragma unroll
    for (int ww = 0; ww < 8; ++ww){
      v0 += ctxred[ww*1024 + r*64 + d];
      v1 += ctxred[ww*1024 + r*64 + d + 1];
    }
    const unsigned int packed = (unsigned int)f2bf(v0) | ((unsigned int)f2bf(v1) << 16);
    *(unsigned int*)(ctxb + (size_t)(b*2048 + q0 + r) * 1024 + h*64 + d) = packed;
  }
}

// ---------------------------------------------------------------- launch
extern "C" void kernel_launch(void* const* d_in, const int* in_sizes, int n_in,
                              void* d_out, int out_size, void* d_ws, size_t ws_size,
                              hipStream_t stream)
{
  const float* X  = (const float*)d_in[0];
  const float* Wq = (const float*)d_in[1];
  const float* bq = (const float*)d_in[2];
  const float* Wk = (const float*)d_in[3];
  const float* bk = (const float*)d_in[4];
  const float* Wv = (const float*)d_in[5];
  const float* bv = (const float*)d_in[6];
  const float* Wo = (const float*)d_in[7];
  const float* bo = (const float*)d_in[8];

  char* ws = (char*)d_ws;
  unsigned short* Xb  = (unsigned short*)(ws);                    // 8 MB
  unsigned short* Qb  = (unsigned short*)(ws + (size_t)( 8u<<20));// 8 MB
  unsigned short* Kbf = (unsigned short*)(ws + (size_t)(16u<<20));// 8 MB
  unsigned short* Vt  = (unsigned short*)(ws + (size_t)(24u<<20));// 8 MB
  unsigned short* Cb  = (unsigned short*)(ws + (size_t)(32u<<20));// 8 MB
  unsigned short* Wqb = (unsigned short*)(ws + (size_t)(40u<<20));// 2 MB
  unsigned short* Wkb = (unsigned short*)(ws + (size_t)(42u<<20));
  unsigned short* Wvb = (unsigned short*)(ws + (size_t)(44u<<20));
  unsigned short* Wob = (unsigned short*)(ws + (size_t)(46u<<20));

  float* out  = (float*)d_out;
  float* attn = out + (size_t)4194304;     // [2][16][2048][2048]

  cvt_bf16<<<4096, 256, 0, stream>>>(X,  Xb,  1048576);
  cvt_bf16<<<1024, 256, 0, stream>>>(Wq, Wqb, 262144);
  cvt_bf16<<<1024, 256, 0, stream>>>(Wk, Wkb, 262144);
  cvt_bf16<<<1024, 256, 0, stream>>>(Wv, Wvb, 262144);
  cvt_bf16<<<1024, 256, 0, stream>>>(Wo, Wob, 262144);

  dim3 qkvgrid(24, 32);
  qkv_gemm<<<qkvgrid, 256, 0, stream>>>(Xb, Wqb, Wkb, Wvb, bq, bk, bv, Qb, Kbf, Vt);

  dim3 agrid(128, 32);
  attn_fused<<<agrid, 512, 0, stream>>>(Qb, Kbf, Vt, attn, Cb);

  dim3 ggrid(8, 32);
  gemm_bt<<<ggrid, 256, 0, stream>>>(Cb, Wob, bo, out, 4096, 1024, 1024);
}

// Round 8
// 346.011 us; speedup vs baseline: 1.3492x; 1.3492x over previous
//
#include <hip/hip_runtime.h>
#include <hip/hip_bf16.h>
#include <cstdint>

typedef __attribute__((ext_vector_type(4))) float f32x4;
typedef __attribute__((ext_vector_type(8))) short bf16x8;

__device__ __forceinline__ unsigned short f2bf(float f){
  union { float f; unsigned int u; } v; v.f = f;
  unsigned int u = v.u;
  u += 0x7FFFu + ((u >> 16) & 1u);   // round-to-nearest-even
  return (unsigned short)(u >> 16);
}
__device__ __forceinline__ float bf2f(unsigned short s){
  union { unsigned int u; float f; } v; v.u = ((unsigned int)s) << 16;
  return v.f;
}

// ---------------------------------------------------------------- cvt f32->bf16
__global__ __launch_bounds__(256) void cvt_bf16(const float* __restrict__ in,
                                                unsigned short* __restrict__ out,
                                                int n4){
  int i = blockIdx.x * 256 + threadIdx.x;
  if (i < n4){
    float4 v = ((const float4*)in)[i];
    ushort4 o;
    o.x = f2bf(v.x); o.y = f2bf(v.y); o.z = f2bf(v.z); o.w = f2bf(v.w);
    ((ushort4*)out)[i] = o;
  }
}

// ---------------------------------------------------------------- fused QKV GEMM
__global__ __launch_bounds__(256) void qkv_gemm(
    const unsigned short* __restrict__ A,
    const unsigned short* __restrict__ W0,
    const unsigned short* __restrict__ W1,
    const unsigned short* __restrict__ W2,
    const float* __restrict__ b0,
    const float* __restrict__ b1,
    const float* __restrict__ b2,
    unsigned short* __restrict__ Qo,
    unsigned short* __restrict__ Ko,
    unsigned short* __restrict__ Vto)
{
  __shared__ unsigned short As[2][128*64];
  __shared__ unsigned short Bs[2][128*64];

  const int K = 1024;
  const int tid = threadIdx.x;
  const int l   = tid & 63;
  const int wid = tid >> 6;
  const int g   = l >> 4;
  const int li  = l & 15;
  const int widx = blockIdx.x >> 3;
  const int m0  = blockIdx.y * 128;
  const int n0  = (blockIdx.x & 7) * 128;
  const int wm  = (wid >> 1) * 64;
  const int wn  = (wid & 1) * 64;
  const int srow = tid >> 3;
  const int sck  = tid & 7;

  const unsigned short* Bw = (widx == 0) ? W0 : ((widx == 1) ? W1 : W2);
  const float* bias        = (widx == 0) ? b0 : ((widx == 1) ? b1 : b2);

  const unsigned short* Ag = A  + (size_t)(m0 + srow) * K + sck * 8;
  const unsigned short* Bg = Bw + (size_t)(n0 + srow) * K + sck * 8;

  f32x4 acc[4][4] = {};
  bf16x8 ra[4], rb[4];
  const int NT = K >> 6;

  #pragma unroll
  for (int r = 0; r < 4; ++r){
    ra[r] = *(const bf16x8*)(Ag + (size_t)(r*32) * K);
    rb[r] = *(const bf16x8*)(Bg + (size_t)(r*32) * K);
  }
  #pragma unroll
  for (int r = 0; r < 4; ++r){
    const int row = srow + r*32;
    const int ck  = sck ^ (row & 7);
    *(bf16x8*)(&As[0][row*64 + ck*8]) = ra[r];
    *(bf16x8*)(&Bs[0][row*64 + ck*8]) = rb[r];
  }
  __syncthreads();

  int cur = 0;
  for (int kt = 0; kt < NT; ++kt){
    if (kt + 1 < NT){
      const int kof = (kt + 1) << 6;
      #pragma unroll
      for (int r = 0; r < 4; ++r){
        ra[r] = *(const bf16x8*)(Ag + (size_t)(r*32) * K + kof);
        rb[r] = *(const bf16x8*)(Bg + (size_t)(r*32) * K + kof);
      }
    }
    #pragma unroll
    for (int kk = 0; kk < 2; ++kk){
      bf16x8 af[4], bfr[4];
      #pragma unroll
      for (int f = 0; f < 4; ++f){
        const int rowa = wm + f*16 + li;
        const int cka  = (kk*4 + g) ^ (rowa & 7);
        af[f] = *(const bf16x8*)(&As[cur][rowa*64 + cka*8]);
        const int rowb = wn + f*16 + li;
        const int ckb  = (kk*4 + g) ^ (rowb & 7);
        bfr[f] = *(const bf16x8*)(&Bs[cur][rowb*64 + ckb*8]);
      }
      #pragma unroll
      for (int fm = 0; fm < 4; ++fm)
        #pragma unroll
        for (int fn = 0; fn < 4; ++fn)
          acc[fm][fn] = __builtin_amdgcn_mfma_f32_16x16x32_bf16(af[fm], bfr[fn], acc[fm][fn], 0, 0, 0);
    }
    __syncthreads();
    if (kt + 1 < NT){
      #pragma unroll
      for (int r = 0; r < 4; ++r){
        const int row = srow + r*32;
        const int ck  = sck ^ (row & 7);
        *(bf16x8*)(&As[cur^1][row*64 + ck*8]) = ra[r];
        *(bf16x8*)(&Bs[cur^1][row*64 + ck*8]) = rb[r];
      }
      __syncthreads();
    }
    cur ^= 1;
  }

  unsigned short* Oqk = (widx == 0) ? Qo : Ko;
  #pragma unroll
  for (int fn = 0; fn < 4; ++fn){
    const int col = n0 + wn + fn*16 + li;
    const float bv = bias[col];
    #pragma unroll
    for (int fm = 0; fm < 4; ++fm){
      #pragma unroll
      for (int j = 0; j < 4; ++j){
        const int row = m0 + wm + fm*16 + g*4 + j;
        const float v = acc[fm][fn][j] + bv;
        if (widx < 2){
          Oqk[(size_t)row * 1024 + col] = f2bf(v);
        } else {
          const int bb = row >> 11;
          const int s  = row & 2047;
          Vto[((size_t)(bb*1024 + col)) * 2048 + s] = f2bf(v);
        }
      }
    }
  }
}

// ---------------------------------------------------------------- out-proj GEMM (f32 out)
__global__ __launch_bounds__(256) void gemm_bt(
    const unsigned short* __restrict__ A,
    const unsigned short* __restrict__ Bw,
    const float* __restrict__ bias,
    float* __restrict__ outp,
    int M, int N, int K)
{
  __shared__ unsigned short As[2][128*64];
  __shared__ unsigned short Bs[2][128*64];

  const int tid = threadIdx.x;
  const int l   = tid & 63;
  const int wid = tid >> 6;
  const int g   = l >> 4;
  const int li  = l & 15;
  const int m0  = blockIdx.y * 128;
  const int n0  = blockIdx.x * 128;
  const int wm  = (wid >> 1) * 64;
  const int wn  = (wid & 1) * 64;
  const int srow = tid >> 3;
  const int sck  = tid & 7;

  const unsigned short* Ag = A  + (size_t)(m0 + srow) * K + sck * 8;
  const unsigned short* Bg = Bw + (size_t)(n0 + srow) * K + sck * 8;

  f32x4 acc[4][4] = {};
  bf16x8 ra[4], rb[4];
  const int NT = K >> 6;

  #pragma unroll
  for (int r = 0; r < 4; ++r){
    ra[r] = *(const bf16x8*)(Ag + (size_t)(r*32) * K);
    rb[r] = *(const bf16x8*)(Bg + (size_t)(r*32) * K);
  }
  #pragma unroll
  for (int r = 0; r < 4; ++r){
    const int row = srow + r*32;
    const int ck  = sck ^ (row & 7);
    *(bf16x8*)(&As[0][row*64 + ck*8]) = ra[r];
    *(bf16x8*)(&Bs[0][row*64 + ck*8]) = rb[r];
  }
  __syncthreads();

  int cur = 0;
  for (int kt = 0; kt < NT; ++kt){
    if (kt + 1 < NT){
      const int kof = (kt + 1) << 6;
      #pragma unroll
      for (int r = 0; r < 4; ++r){
        ra[r] = *(const bf16x8*)(Ag + (size_t)(r*32) * K + kof);
        rb[r] = *(const bf16x8*)(Bg + (size_t)(r*32) * K + kof);
      }
    }
    #pragma unroll
    for (int kk = 0; kk < 2; ++kk){
      bf16x8 af[4], bfr[4];
      #pragma unroll
      for (int f = 0; f < 4; ++f){
        const int rowa = wm + f*16 + li;
        const int cka  = (kk*4 + g) ^ (rowa & 7);
        af[f] = *(const bf16x8*)(&As[cur][rowa*64 + cka*8]);
        const int rowb = wn + f*16 + li;
        const int ckb  = (kk*4 + g) ^ (rowb & 7);
        bfr[f] = *(const bf16x8*)(&Bs[cur][rowb*64 + ckb*8]);
      }
      #pragma unroll
      for (int fm = 0; fm < 4; ++fm)
        #pragma unroll
        for (int fn = 0; fn < 4; ++fn)
          acc[fm][fn] = __builtin_amdgcn_mfma_f32_16x16x32_bf16(af[fm], bfr[fn], acc[fm][fn], 0, 0, 0);
    }
    __syncthreads();
    if (kt + 1 < NT){
      #pragma unroll
      for (int r = 0; r < 4; ++r){
        const int row = srow + r*32;
        const int ck  = sck ^ (row & 7);
        *(bf16x8*)(&As[cur^1][row*64 + ck*8]) = ra[r];
        *(bf16x8*)(&Bs[cur^1][row*64 + ck*8]) = rb[r];
      }
      __syncthreads();
    }
    cur ^= 1;
  }

  #pragma unroll
  for (int fn = 0; fn < 4; ++fn){
    const int col = n0 + wn + fn*16 + li;
    const float bv = bias[col];
    #pragma unroll
    for (int fm = 0; fm < 4; ++fm){
      #pragma unroll
      for (int j = 0; j < 4; ++j){
        const int row = m0 + wm + fm*16 + g*4 + j;
        outp[(size_t)row * N + col] = acc[fm][fn][j] + bv;
      }
    }
  }
}

// ---------------------------------------------------------------- fused attention (R7)
// R4 single-pass structure + DEEP LOAD BATCHING: QK^T and PV each run in two halves,
// each half issues 16 independent 16B global loads back-to-back (64 VGPRs) before any
// consume — 16-deep VMEM pipeline instead of ~2. No in-loop fences.
__global__ __launch_bounds__(512, 4) void attn_fused(
    const unsigned short* __restrict__ Qb,   // [4096][1024] bf16
    const unsigned short* __restrict__ Kb,   // [4096][1024] bf16
    const unsigned short* __restrict__ Vt,   // [2048][2048] bf16  ([b*1024+hid][s])
    float* __restrict__ attn,                // [2][16][2048][2048] f32
    unsigned short* __restrict__ ctxb)       // [4096][1024] bf16
{
  __shared__ float red[128];
  __shared__ __align__(16) unsigned short Pb[16 * 2048];   // 64 KB; aliased as ctxred after use
  float* ctxred = (float*)Pb;                               // [8][16][64] f32
  char*  Pbb    = (char*)Pb;

  const int tid = threadIdx.x;
  const int l   = tid & 63;
  const int w   = tid >> 6;
  const int g   = l >> 4;     // 0..3
  const int li  = l & 15;     // q-row within block
  const int q0  = blockIdx.x * 16;
  const int bh  = blockIdx.y;
  const int b   = bh >> 4;
  const int h   = bh & 15;

  // Q fragments (B-operand: col = li = q-row, k = g*8+j within each 32-wide k-step)
  const size_t qrow = (size_t)(b*2048 + q0 + li) * 1024 + h*64 + g*8;
  const bf16x8 aq0 = *(const bf16x8*)(Qb + qrow);
  const bf16x8 aq1 = *(const bf16x8*)(Qb + qrow + 32);

  const unsigned short* Kbase = Kb + (size_t)(b*2048) * 1024 + h*64 + g*8;

  // ---- QK^T + exp + P->LDS, two halves of 8 key-frags; 16 loads in flight per half
  float ls = 0.f;
  const int swz = li << 3;                  // XOR on byte-addr bits 3..6, keyed by row
  #pragma unroll
  for (int hf = 0; hf < 2; ++hf){
    bf16x8 bk[16];
    #pragma unroll
    for (int cf = 0; cf < 8; ++cf){
      const unsigned short* kr = Kbase + (size_t)(w*256 + hf*128 + cf*16 + li) * 1024;
      bk[cf*2]   = *(const bf16x8*)(kr);
      bk[cf*2+1] = *(const bf16x8*)(kr + 32);
    }
    #pragma unroll
    for (int cf = 0; cf < 8; ++cf){
      f32x4 t = {};
      t = __builtin_amdgcn_mfma_f32_16x16x32_bf16(bk[cf*2],   aq0, t, 0, 0, 0);
      t = __builtin_amdgcn_mfma_f32_16x16x32_bf16(bk[cf*2+1], aq1, t, 0, 0, 0);
      const float p0 = __expf(t[0] * 0.125f);
      const float p1 = __expf(t[1] * 0.125f);
      const float p2 = __expf(t[2] * 0.125f);
      const float p3 = __expf(t[3] * 0.125f);
      ls += p0 + p1 + p2 + p3;
      ushort4 u;
      u.x = f2bf(p0); u.y = f2bf(p1); u.z = f2bf(p2); u.w = f2bf(p3);
      const int colb = w*512 + (hf*8 + cf)*32 + g*8;   // byte col = key*2
      *(ushort4*)(Pbb + li*4096 + (colb ^ swz)) = u;
    }
  }

  // ---- row sums: reduce over g (lanes ^16, ^32), then cross-wave via LDS
  ls += __shfl_xor(ls, 16);
  ls += __shfl_xor(ls, 32);
  if (l < 16) red[w*16 + l] = ls;
  __syncthreads();                            // publishes Pb + red

  // ---- PV over own key slice (unnormalized P); V loads batched 16-deep
  f32x4 pv[4] = {};
  const unsigned short* Vbase = Vt + (size_t)(b*1024 + h*64) * 2048 + w*256;
  #pragma unroll
  for (int vh = 0; vh < 2; ++vh){
    bf16x8 vb[16];
    #pragma unroll
    for (int kt = 0; kt < 4; ++kt)
      #pragma unroll
      for (int df = 0; df < 4; ++df)
        vb[kt*4+df] = *(const bf16x8*)(Vbase + (size_t)(df*16 + li) * 2048 + (vh*4+kt)*32 + g*8);
    #pragma unroll
    for (int kt = 0; kt < 4; ++kt){
      const int colb2 = w*512 + (vh*4+kt)*64 + g*16;
      const ushort4 plo = *(const ushort4*)(Pbb + li*4096 + ( colb2      ^ swz));
      const ushort4 phi = *(const ushort4*)(Pbb + li*4096 + ((colb2 + 8) ^ swz));
      bf16x8 pa;
      pa[0] = plo.x; pa[1] = plo.y; pa[2] = plo.z; pa[3] = plo.w;
      pa[4] = phi.x; pa[5] = phi.y; pa[6] = phi.z; pa[7] = phi.w;
      #pragma unroll
      for (int df = 0; df < 4; ++df)
        pv[df] = __builtin_amdgcn_mfma_f32_16x16x32_bf16(pa, vb[kt*4+df], pv[df], 0, 0, 0);
    }
  }

  // ctx rescale factors for rows g*4+j
  float r4[4];
  #pragma unroll
  for (int j = 0; j < 4; ++j){
    float dj = 0.f;
    #pragma unroll
    for (int ww = 0; ww < 8; ++ww) dj += red[ww*16 + g*4 + j];
    r4[j] = 1.0f / dj;
  }

  // ---- attn stores, COALESCED readback: wave w stores rows 2w, 2w+1.
  // Per c0 iter: 64 lanes read 512B of the Pb row, store 1KB contiguous (NT).
  {
    #pragma unroll
    for (int rr = 0; rr < 2; ++rr){
      const int r = 2*w + rr;
      float dj = 0.f;
      #pragma unroll
      for (int ww = 0; ww < 8; ++ww) dj += red[ww*16 + r];
      const float rv = 1.0f / dj;
      const int key = r << 3;
      float* arow = attn + ((size_t)bh * 2048 + q0 + r) * 2048;
      #pragma unroll
      for (int c0 = 0; c0 < 8; ++c0){
        const int cb = c0*512 + l*8;          // byte col in Pb row (= key*2)
        const ushort4 u = *(const ushort4*)(Pbb + r*4096 + (cb ^ key));
        f32x4 o;
        o[0] = bf2f(u.x) * rv; o[1] = bf2f(u.y) * rv;
        o[2] = bf2f(u.z) * rv; o[3] = bf2f(u.w) * rv;
        __builtin_nontemporal_store(o, (f32x4*)(arow + c0*256 + l*4));
      }
    }
  }

  __syncthreads();                            // all waves done reading Pb; reuse as ctxred
  #pragma unroll
  for (int df = 0; df < 4; ++df){
    #pragma unroll
    for (int j = 0; j < 4; ++j)
      ctxred[w*1024 + (g*4 + j)*64 + df*16 + li] = pv[df][j] * r4[j];
  }
  __syncthreads();
  {
    const int idx = tid * 2;                  // 512 threads x 2 = 16*64 outputs
    const int r = idx >> 6;
    const int d = idx & 63;
    float v0 = 0.f, v1 = 0.f;
    #pragma unroll
    for (int ww = 0; ww < 8; ++ww){
      v0 += ctxred[ww*1024 + r*64 + d];
      v1 += ctxred[ww*1024 + r*64 + d + 1];
    }
    const unsigned int packed = (unsigned int)f2bf(v0) | ((unsigned int)f2bf(v1) << 16);
    *(unsigned int*)(ctxb + (size_t)(b*2048 + q0 + r) * 1024 + h*64 + d) = packed;
  }
}

// ---------------------------------------------------------------- launch
extern "C" void kernel_launch(void* const* d_in, const int* in_sizes, int n_in,
                              void* d_out, int out_size, void* d_ws, size_t ws_size,
                              hipStream_t stream)
{
  const float* X  = (const float*)d_in[0];
  const float* Wq = (const float*)d_in[1];
  const float* bq = (const float*)d_in[2];
  const float* Wk = (const float*)d_in[3];
  const float* bk = (const float*)d_in[4];
  const float* Wv = (const float*)d_in[5];
  const float* bv = (const float*)d_in[6];
  const float* Wo = (const float*)d_in[7];
  const float* bo = (const float*)d_in[8];

  char* ws = (char*)d_ws;
  unsigned short* Xb  = (unsigned short*)(ws);                    // 8 MB
  unsigned short* Qb  = (unsigned short*)(ws + (size_t)( 8u<<20));// 8 MB
  unsigned short* Kbf = (unsigned short*)(ws + (size_t)(16u<<20));// 8 MB
  unsigned short* Vt  = (unsigned short*)(ws + (size_t)(24u<<20));// 8 MB
  unsigned short* Cb  = (unsigned short*)(ws + (size_t)(32u<<20));// 8 MB
  unsigned short* Wqb = (unsigned short*)(ws + (size_t)(40u<<20));// 2 MB
  unsigned short* Wkb = (unsigned short*)(ws + (size_t)(42u<<20));
  unsigned short* Wvb = (unsigned short*)(ws + (size_t)(44u<<20));
  unsigned short* Wob = (unsigned short*)(ws + (size_t)(46u<<20));

  float* out  = (float*)d_out;
  float* attn = out + (size_t)4194304;     // [2][16][2048][2048]

  cvt_bf16<<<4096, 256, 0, stream>>>(X,  Xb,  1048576);
  cvt_bf16<<<1024, 256, 0, stream>>>(Wq, Wqb, 262144);
  cvt_bf16<<<1024, 256, 0, stream>>>(Wk, Wkb, 262144);
  cvt_bf16<<<1024, 256, 0, stream>>>(Wv, Wvb, 262144);
  cvt_bf16<<<1024, 256, 0, stream>>>(Wo, Wob, 262144);

  dim3 qkvgrid(24, 32);
  qkv_gemm<<<qkvgrid, 256, 0, stream>>>(Xb, Wqb, Wkb, Wvb, bq, bk, bv, Qb, Kbf, Vt);

  dim3 agrid(128, 32);
  attn_fused<<<agrid, 512, 0, stream>>>(Qb, Kbf, Vt, attn, Cb);

  dim3 ggrid(8, 32);
  gemm_bt<<<ggrid, 256, 0, stream>>>(Cb, Wob, bo, out, 4096, 1024, 1024);
}